// Round 1
// baseline (391.266 us; speedup 1.0000x reference)
//
#include <hip/hip_runtime.h>
#include <math.h>

#define Hd 256
#define Wd 256
#define Cd 128
#define BIGV 1.0e9f

static __device__ __forceinline__ float softplus_f(float x) {
    return fmaxf(x, 0.0f) + log1pf(expf(-fabsf(x)));
}

// ---------------------------------------------------------------------------
// Kernel 1: per-pixel fused feature work.
// 16x16 pixel tile per block (256 threads, 1 px/thread), 18x18 halo staging,
// channel-chunked (32 ch) in LDS with planar [ch][px] layout (stride 325).
// ---------------------------------------------------------------------------
#define TILE 16
#define HPX 18
#define PXN 324          // 18*18
#define SP  325          // padded plane stride (325 % 32 != 0)
#define CHUNK 32

__global__ __launch_bounds__(256) void k_pixel(
    const float* __restrict__ feat,
    const float* __restrict__ w1, const float* __restrict__ b1,
    const float* __restrict__ w2, const float* __restrict__ b2,
    const int*   __restrict__ endn,
    float* __restrict__ out,
    float* __restrict__ costP,
    float* __restrict__ geoG, float* __restrict__ varG,
    float* __restrict__ omgG, float* __restrict__ absG)
{
    __shared__ float stage[CHUNK * SP];
    __shared__ float normL[PXN];
    __shared__ float w1L[Cd * 32];
    __shared__ float endfL[64];

    const int t  = threadIdx.x;
    const int r0 = blockIdx.y * TILE;
    const int c0 = blockIdx.x * TILE;

    for (int i = t; i < Cd * 32; i += 256) w1L[i] = w1[i];
    if (t < 64) {
        int ep = endn[0] * Wd + endn[1];
        endfL[t] = feat[ep * Cd + t];
    }

    const int lr = t >> 4, lc = t & 15;
    const int r = r0 + lr, c = c0 + lc;
    const int px0 = (lr + 1) * HPX + (lc + 1);

    float hA[32];
#pragma unroll
    for (int j = 0; j < 32; ++j) hA[j] = 0.0f;
    float dotv[8];
#pragma unroll
    for (int j = 0; j < 8; ++j) dotv[j] = 0.0f;
    float gm_acc = 0.0f, var_acc = 0.0f, abs_acc = 0.0f;

    for (int ch0 = 0; ch0 < Cd; ch0 += CHUNK) {
        __syncthreads();   // protect stage (and w1L on first pass)
        // ---- stage chunk: i -> px = i>>3, f4 = i&7 (8 lanes read 128B/px)
        for (int i = t; i < PXN * 8; i += 256) {
            int px = i >> 3, f4 = i & 7;
            int pr = px / HPX;
            int pc = px - pr * HPX;
            int gr = r0 - 1 + pr, gc = c0 - 1 + pc;
            float4 v = make_float4(0.f, 0.f, 0.f, 0.f);
            if ((unsigned)gr < Hd && (unsigned)gc < Wd) {
                v = *reinterpret_cast<const float4*>(
                        &feat[(((gr << 8) + gc) * Cd) + ch0 + (f4 << 2)]);
            }
            int chb = f4 << 2;
            stage[(chb + 0) * SP + px] = v.x;
            stage[(chb + 1) * SP + px] = v.y;
            stage[(chb + 2) * SP + px] = v.z;
            stage[(chb + 3) * SP + px] = v.w;
        }
        __syncthreads();
        // ---- per-pixel norm accumulation (all 324 halo pixels)
        for (int px = t; px < PXN; px += 256) {
            float s = 0.0f;
#pragma unroll
            for (int ch = 0; ch < CHUNK; ++ch) {
                float v = stage[ch * SP + px];
                s = fmaf(v, v, s);
            }
            if (ch0 == 0) normL[px] = s; else normL[px] += s;
        }
        // ---- fused per-channel compute for own pixel
        const bool is_hf = (ch0 >= 64);   // C_lf = 64, chunk never straddles
        for (int ch = 0; ch < CHUNK; ++ch) {
            const float* pl = stage + ch * SP + px0;
            float x  = pl[0];
            float n0 = pl[-HPX - 1], n1 = pl[-HPX], n2 = pl[-HPX + 1];
            float n3 = pl[-1],                      n4 = pl[1];
            float n5 = pl[HPX - 1],  n6 = pl[HPX],  n7 = pl[HPX + 1];

            // sobel (correlation vs convolution sign-irrelevant: squared)
            float gx = (n2 + 2.f * n4 + n7) - (n0 + 2.f * n3 + n5);
            float gy = (n5 + 2.f * n6 + n7) - (n0 + 2.f * n1 + n2);
            gm_acc += sqrtf(gx * gx + gy * gy);

            if (is_hf) {
                float s1 = x + n0 + n1 + n2 + n3 + n4 + n5 + n6 + n7;
                float s2 = x*x + n0*n0 + n1*n1 + n2*n2 + n3*n3 + n4*n4
                         + n5*n5 + n6*n6 + n7*n7;
                float m = s1 * (1.0f / 9.0f);
                var_acc += s2 * (1.0f / 9.0f) - m * m;
            } else {
                float dlf = x - endfL[ch0 + ch];
                abs_acc = fmaf(dlf, dlf, abs_acc);
            }

            dotv[0] = fmaf(x, n0, dotv[0]);
            dotv[1] = fmaf(x, n1, dotv[1]);
            dotv[2] = fmaf(x, n2, dotv[2]);
            dotv[3] = fmaf(x, n3, dotv[3]);
            dotv[4] = fmaf(x, n4, dotv[4]);
            dotv[5] = fmaf(x, n5, dotv[5]);
            dotv[6] = fmaf(x, n6, dotv[6]);
            dotv[7] = fmaf(x, n7, dotv[7]);

            const float* wrow = &w1L[(ch0 + ch) << 5];
#pragma unroll
            for (int j = 0; j < 32; ++j) hA[j] = fmaf(x, wrow[j], hA[j]);
        }
    }
    __syncthreads();   // normL complete before neighbor reads

    // ---- finalize
    const int p = (r << 8) + c;
    float geo  = gm_acc * (1.0f / 128.0f);
    float absp = sqrtf(abs_acc);
    float o = b2[0];
#pragma unroll
    for (int j = 0; j < 32; ++j) {
        float hj = fmaxf(hA[j] + b1[j], 0.0f);
        o = fmaf(hj, w2[j], o);
    }
    float omg = 1.0f / (1.0f + expf(-o));
    geoG[p] = geo; varG[p] = var_acc; omgG[p] = omg; absG[p] = absp;

    float np = fmaxf(sqrtf(normL[px0]), 1e-12f);
    const int drr[8] = {-1,-1,-1, 0, 0, 1, 1, 1};
    const int dcc[8] = {-1, 0, 1,-1, 1,-1, 0, 1};
    const int nof[8] = {-HPX-1,-HPX,-HPX+1,-1,1,HPX-1,HPX,HPX+1};
#pragma unroll
    for (int j = 0; j < 8; ++j) {
        int nr = r + drr[j], nc = c + dcc[j];
        float cj;
        if ((unsigned)nr < Hd && (unsigned)nc < Wd) {
            float nn = fmaxf(sqrtf(normL[px0 + nof[j]]), 1e-12f);
            cj = 1.0f - dotv[j] / (np * nn);
        } else {
            cj = BIGV;
        }
        costP[(j << 16) + p] = cj;
        out[p * 10 + 1 + j]  = cj;
    }
}

// ---------------------------------------------------------------------------
// Kernel 2: heuristic combine + dist init
// ---------------------------------------------------------------------------
__global__ __launch_bounds__(256) void k_combine(
    const float* __restrict__ geoG, const float* __restrict__ varG,
    const float* __restrict__ omgG, const float* __restrict__ absG,
    const float* __restrict__ dlt, const float* __restrict__ gmm,
    const float* __restrict__ bta,
    const int* __restrict__ startn, const int* __restrict__ endn,
    float* __restrict__ out, float* __restrict__ distA)
{
    int p = blockIdx.x * 256 + threadIdx.x;
    float d = softplus_f(dlt[0]);
    float g = softplus_f(gmm[0]);
    float b = softplus_f(bta[0]);
    float vend = varG[endn[0] * Wd + endn[1]];
    float omg  = omgG[p];
    float heur = d * geoG[p] + omg * g * (vend - varG[p])
               + (1.0f - omg) * b * absG[p];
    out[p * 10] = fmaxf(heur, 0.0f);
    int sp = startn[0] * Wd + startn[1];
    distA[p] = (p == sp) ? 0.0f : BIGV;
}

// ---------------------------------------------------------------------------
// Kernel 3 (x32 phases): 8 exact Jacobi min-plus iterations per phase.
// 16x16 core + halo 8 => 32x32 LDS tile, dbl-buffered; own-cell costs in regs
// (symmetric rewrite: d[p] = min(dist[p], min_j dist[p+Dj] + cost[p,j])).
// ---------------------------------------------------------------------------
#define TSTR 35   // LDS row stride (35 % 32 = 3)

__global__ __launch_bounds__(256) void k_phase(
    const float* __restrict__ src, float* __restrict__ dst,
    const float* __restrict__ costP)
{
    __shared__ float D[2][34 * TSTR];
    const int t  = threadIdx.x;
    const int tc = t & 31;          // tile col 0..31
    const int q  = t >> 5;          // row group (4 rows each)
    const int r0 = (int)blockIdx.y * 16 - 8;
    const int c0 = (int)blockIdx.x * 16 - 8;

    for (int i = t; i < 2 * 34 * TSTR; i += 256) (&D[0][0])[i] = BIGV;
    __syncthreads();   // ring must be BIG before interior writes

    float cR[4][8];
#pragma unroll
    for (int i = 0; i < 4; ++i) {
        int lr = (q << 2) + i;
        int gr = r0 + lr, gc = c0 + tc;
        bool in = ((unsigned)gr < Hd) && ((unsigned)gc < Wd);
        int p = (gr << 8) + gc;
        D[0][(lr + 1) * TSTR + tc + 1] = in ? src[p] : BIGV;
#pragma unroll
        for (int j = 0; j < 8; ++j)
            cR[i][j] = in ? costP[(j << 16) + p] : BIGV;
    }
    __syncthreads();

    for (int it = 0; it < 8; ++it) {
        const float* Dc = D[it & 1];
        float*       Dn = D[1 - (it & 1)];
#pragma unroll
        for (int i = 0; i < 4; ++i) {
            int lr = (q << 2) + i;
            int b0 = (lr + 1) * TSTR + tc + 1;
            float best = Dc[b0];
            best = fminf(best, Dc[b0 - TSTR - 1] + cR[i][0]);
            best = fminf(best, Dc[b0 - TSTR    ] + cR[i][1]);
            best = fminf(best, Dc[b0 - TSTR + 1] + cR[i][2]);
            best = fminf(best, Dc[b0 - 1       ] + cR[i][3]);
            best = fminf(best, Dc[b0 + 1       ] + cR[i][4]);
            best = fminf(best, Dc[b0 + TSTR - 1] + cR[i][5]);
            best = fminf(best, Dc[b0 + TSTR    ] + cR[i][6]);
            best = fminf(best, Dc[b0 + TSTR + 1] + cR[i][7]);
            Dn[b0] = best;
        }
        __syncthreads();
    }
    // after 8 iters result is in D[0]; write 16x16 core
    if (tc >= 8 && tc < 24 && q >= 2 && q < 6) {
#pragma unroll
        for (int i = 0; i < 4; ++i) {
            int lr = (q << 2) + i;
            int gr = r0 + lr, gc = c0 + tc;
            dst[(gr << 8) + gc] = D[0][(lr + 1) * TSTR + tc + 1];
        }
    }
}

// ---------------------------------------------------------------------------
// Kernel 4: write dist channel
// ---------------------------------------------------------------------------
__global__ __launch_bounds__(256) void k_finish(
    const float* __restrict__ dist, float* __restrict__ out)
{
    int p = blockIdx.x * 256 + threadIdx.x;
    out[p * 10 + 9] = fminf(dist[p], BIGV);
}

// ---------------------------------------------------------------------------
extern "C" void kernel_launch(void* const* d_in, const int* in_sizes, int n_in,
                              void* d_out, int out_size, void* d_ws, size_t ws_size,
                              hipStream_t stream)
{
    const float* feat  = (const float*)d_in[0];
    const float* dlt   = (const float*)d_in[1];
    const float* gmm   = (const float*)d_in[2];
    const float* bta   = (const float*)d_in[3];
    const float* w1    = (const float*)d_in[4];
    const float* b1    = (const float*)d_in[5];
    const float* w2    = (const float*)d_in[6];
    const float* b2    = (const float*)d_in[7];
    const int*   startn= (const int*)d_in[8];
    const int*   endn  = (const int*)d_in[9];
    float* out = (float*)d_out;
    float* ws  = (float*)d_ws;

    float* costP = ws;                    // 8 * 65536 planar cost
    float* geoG  = ws + 8 * 65536;
    float* varG  = geoG + 65536;
    float* omgG  = varG + 65536;
    float* absG  = omgG + 65536;
    float* distA = absG + 65536;
    float* distB = distA + 65536;         // total 14*65536 floats = 3.67 MB

    dim3 g16(16, 16);
    k_pixel<<<g16, 256, 0, stream>>>(feat, w1, b1, w2, b2, endn,
                                     out, costP, geoG, varG, omgG, absG);
    k_combine<<<256, 256, 0, stream>>>(geoG, varG, omgG, absG,
                                       dlt, gmm, bta, startn, endn, out, distA);
    float* a = distA; float* bb = distB;
    for (int ph = 0; ph < 32; ++ph) {     // 32 phases x 8 iters = 256 exact
        k_phase<<<g16, 256, 0, stream>>>(a, bb, costP);
        float* tmp = a; a = bb; bb = tmp;
    }
    k_finish<<<256, 256, 0, stream>>>(a, out);
}

// Round 2
// 380.924 us; speedup vs baseline: 1.0271x; 1.0271x over previous
//
#include <hip/hip_runtime.h>
#include <math.h>

#define Hd 256
#define Wd 256
#define Cd 128
#define BIGV 1.0e9f

static __device__ __forceinline__ float softplus_f(float x) {
    return fmaxf(x, 0.0f) + log1pf(expf(-fabsf(x)));
}

// ---------------------------------------------------------------------------
// Kernel 1: per-pixel fused feature work.
// 16x16 tile/block, 18x18 halo, channels staged 32 at a time as float4-packed
// planes S4[g][px] (g = 4-channel group). Stencil reads are ds_read_b128
// (9 per 4 channels). MLP weights read from global with wave-uniform address
// -> scalar loads (no LDS issue cost). Global staging double-buffered in regs.
// ---------------------------------------------------------------------------
#define TILE 16
#define HPX 18
#define PXN 324           // 18*18
#define SP4 325           // float4-plane stride
#define NL  11            // ceil(324*8 / 256)

__global__ __launch_bounds__(256, 1) void k_pixel(
    const float* __restrict__ feat,
    const float* __restrict__ w1, const float* __restrict__ b1,
    const float* __restrict__ w2, const float* __restrict__ b2,
    const int*   __restrict__ endn,
    float* __restrict__ out,
    float* __restrict__ costP,
    float* __restrict__ geoG, float* __restrict__ varG,
    float* __restrict__ omgG, float* __restrict__ absG)
{
    __shared__ float4 S4[8 * SP4];
    __shared__ float  normL[PXN];

    const int t  = threadIdx.x;
    const int r0 = blockIdx.y * TILE;
    const int c0 = blockIdx.x * TILE;
    const int lr = t >> 4, lc = t & 15;
    const int r = r0 + lr, c = c0 + lc;
    const int px0 = (lr + 1) * HPX + (lc + 1);

    const int ep = endn[0] * Wd + endn[1];              // uniform
    const float* __restrict__ endf = feat + (size_t)ep * Cd;

    // ---- prefetch chunk 0 into registers
    float4 vbuf[NL];
#pragma unroll
    for (int k = 0; k < NL; ++k) {
        int i = t + (k << 8);
        float4 v = make_float4(0.f, 0.f, 0.f, 0.f);
        if (i < PXN * 8) {
            int px = i >> 3, g = i & 7;
            int pr = px / HPX, pc = px - pr * HPX;
            int gr = r0 - 1 + pr, gc = c0 - 1 + pc;
            if ((unsigned)gr < Hd && (unsigned)gc < Wd)
                v = *(const float4*)&feat[((gr << 8) + gc) * Cd + (g << 2)];
        }
        vbuf[k] = v;
    }

    float4 hv[8];
#pragma unroll
    for (int j = 0; j < 8; ++j) hv[j] = make_float4(0.f, 0.f, 0.f, 0.f);
    float dotv[8];
#pragma unroll
    for (int j = 0; j < 8; ++j) dotv[j] = 0.0f;
    float gm_acc = 0.0f, var_acc = 0.0f, abs_acc = 0.0f;

    for (int ch0 = 0; ch0 < Cd; ch0 += 32) {
        __syncthreads();                 // previous chunk fully consumed
        // ---- commit prefetched regs to LDS
#pragma unroll
        for (int k = 0; k < NL; ++k) {
            int i = t + (k << 8);
            if (i < PXN * 8) S4[(i & 7) * SP4 + (i >> 3)] = vbuf[k];
        }
        __syncthreads();
        // ---- issue prefetch for next chunk (hidden under compute)
        if (ch0 < 96) {
            const int nch = ch0 + 32;
#pragma unroll
            for (int k = 0; k < NL; ++k) {
                int i = t + (k << 8);
                float4 v = make_float4(0.f, 0.f, 0.f, 0.f);
                if (i < PXN * 8) {
                    int px = i >> 3, g = i & 7;
                    int pr = px / HPX, pc = px - pr * HPX;
                    int gr = r0 - 1 + pr, gc = c0 - 1 + pc;
                    if ((unsigned)gr < Hd && (unsigned)gc < Wd)
                        v = *(const float4*)&feat[((gr << 8) + gc) * Cd + nch + (g << 2)];
                }
                vbuf[k] = v;
            }
        }
        // ---- per-pixel norm partials (all 324 halo pixels)
        for (int px = t; px < PXN; px += 256) {
            float s = 0.0f;
#pragma unroll
            for (int g = 0; g < 8; ++g) {
                float4 q = S4[g * SP4 + px];
                s = fmaf(q.x, q.x, fmaf(q.y, q.y, fmaf(q.z, q.z, fmaf(q.w, q.w, s))));
            }
            normL[px] = (ch0 == 0) ? s : normL[px] + s;
        }
        // ---- fused per-channel compute for own pixel (4 ch per b128 group)
        const bool is_hf = (ch0 >= 64);
#pragma unroll
        for (int g = 0; g < 8; ++g) {
            const float4* __restrict__ Sg = &S4[g * SP4];
            float4 X  = Sg[px0];
            float4 A0 = Sg[px0 - HPX - 1], A1 = Sg[px0 - HPX], A2 = Sg[px0 - HPX + 1];
            float4 A3 = Sg[px0 - 1],       A4 = Sg[px0 + 1];
            float4 A5 = Sg[px0 + HPX - 1], A6 = Sg[px0 + HPX], A7 = Sg[px0 + HPX + 1];
            const float* __restrict__ wbase = w1 + (((ch0 + (g << 2))) << 5);
#pragma unroll
            for (int cc = 0; cc < 4; ++cc) {
                float x  = ((const float*)&X)[cc];
                float n0 = ((const float*)&A0)[cc];
                float n1 = ((const float*)&A1)[cc];
                float n2 = ((const float*)&A2)[cc];
                float n3 = ((const float*)&A3)[cc];
                float n4 = ((const float*)&A4)[cc];
                float n5 = ((const float*)&A5)[cc];
                float n6 = ((const float*)&A6)[cc];
                float n7 = ((const float*)&A7)[cc];

                float gx = (n2 + 2.f * n4 + n7) - (n0 + 2.f * n3 + n5);
                float gy = (n5 + 2.f * n6 + n7) - (n0 + 2.f * n1 + n2);
                gm_acc += sqrtf(fmaf(gx, gx, gy * gy));

                if (is_hf) {
                    float s1 = x + n0 + n1 + n2 + n3 + n4 + n5 + n6 + n7;
                    float s2 = fmaf(x, x, fmaf(n0, n0, fmaf(n1, n1, fmaf(n2, n2,
                               fmaf(n3, n3, fmaf(n4, n4, fmaf(n5, n5,
                               fmaf(n6, n6, n7 * n7))))))));
                    float m = s1 * (1.0f / 9.0f);
                    var_acc += s2 * (1.0f / 9.0f) - m * m;
                } else {
                    float dlf = x - endf[ch0 + (g << 2) + cc];   // uniform s_load
                    abs_acc = fmaf(dlf, dlf, abs_acc);
                }

                dotv[0] = fmaf(x, n0, dotv[0]);
                dotv[1] = fmaf(x, n1, dotv[1]);
                dotv[2] = fmaf(x, n2, dotv[2]);
                dotv[3] = fmaf(x, n3, dotv[3]);
                dotv[4] = fmaf(x, n4, dotv[4]);
                dotv[5] = fmaf(x, n5, dotv[5]);
                dotv[6] = fmaf(x, n6, dotv[6]);
                dotv[7] = fmaf(x, n7, dotv[7]);

                const float4* __restrict__ wr4 = (const float4*)(wbase + (cc << 5));
#pragma unroll
                for (int j4 = 0; j4 < 8; ++j4) {
                    float4 wv = wr4[j4];                         // uniform s_load
                    hv[j4].x = fmaf(x, wv.x, hv[j4].x);
                    hv[j4].y = fmaf(x, wv.y, hv[j4].y);
                    hv[j4].z = fmaf(x, wv.z, hv[j4].z);
                    hv[j4].w = fmaf(x, wv.w, hv[j4].w);
                }
            }
        }
    }
    __syncthreads();   // normL complete before neighbor reads

    // ---- finalize
    const int p = (r << 8) + c;
    float geo  = gm_acc * (1.0f / 128.0f);
    float absp = sqrtf(abs_acc);
    float o = b2[0];
#pragma unroll
    for (int j4 = 0; j4 < 8; ++j4) {
#pragma unroll
        for (int cc = 0; cc < 4; ++cc) {
            int j = (j4 << 2) + cc;
            float hj = fmaxf(((const float*)&hv[j4])[cc] + b1[j], 0.0f);
            o = fmaf(hj, w2[j], o);
        }
    }
    float omg = 1.0f / (1.0f + expf(-o));
    geoG[p] = geo; varG[p] = var_acc; omgG[p] = omg; absG[p] = absp;

    float np = fmaxf(sqrtf(normL[px0]), 1e-12f);
    const int drr[8] = {-1,-1,-1, 0, 0, 1, 1, 1};
    const int dcc[8] = {-1, 0, 1,-1, 1,-1, 0, 1};
    const int nof[8] = {-HPX-1,-HPX,-HPX+1,-1,1,HPX-1,HPX,HPX+1};
#pragma unroll
    for (int j = 0; j < 8; ++j) {
        int nr = r + drr[j], nc = c + dcc[j];
        float cj;
        if ((unsigned)nr < Hd && (unsigned)nc < Wd) {
            float nn = fmaxf(sqrtf(normL[px0 + nof[j]]), 1e-12f);
            cj = 1.0f - dotv[j] / (np * nn);
        } else {
            cj = BIGV;
        }
        costP[(j << 16) + p] = cj;
        out[p * 10 + 1 + j]  = cj;
    }
}

// ---------------------------------------------------------------------------
// Kernel 2: heuristic combine
// ---------------------------------------------------------------------------
__global__ __launch_bounds__(256) void k_combine(
    const float* __restrict__ geoG, const float* __restrict__ varG,
    const float* __restrict__ omgG, const float* __restrict__ absG,
    const float* __restrict__ dlt, const float* __restrict__ gmm,
    const float* __restrict__ bta, const int* __restrict__ endn,
    float* __restrict__ out)
{
    int p = blockIdx.x * 256 + threadIdx.x;
    float d = softplus_f(dlt[0]);
    float g = softplus_f(gmm[0]);
    float b = softplus_f(bta[0]);
    float vend = varG[endn[0] * Wd + endn[1]];
    float omg  = omgG[p];
    float heur = d * geoG[p] + omg * g * (vend - varG[p])
               + (1.0f - omg) * b * absG[p];
    out[p * 10] = fmaxf(heur, 0.0f);
}

// ---------------------------------------------------------------------------
// Kernel 3 (x32 phases): 8 exact Jacobi min-plus iterations per phase.
// 16x16 core + halo 8 (32x32 tile + BIG ring), double-buffered LDS.
// Column register-rotation: 18 reads / 4 cells (vs 36). Active-row-group
// skip: margin shrinks 7->0. FIRST computes dist0 inline; LAST writes out.
// ---------------------------------------------------------------------------
#define TSTR 35

template<int FIRST, int LAST>
__global__ __launch_bounds__(256, 1) void k_phase(
    const float* __restrict__ src, float* __restrict__ dst,
    const float* __restrict__ costP, const int* __restrict__ startn,
    float* __restrict__ outp)
{
    __shared__ float D[2][34 * TSTR];
    const int t  = threadIdx.x;
    const int tc = t & 31;
    const int q  = t >> 5;
    const int rbase = q << 2;
    const int r0 = (int)blockIdx.y * 16 - 8;
    const int c0 = (int)blockIdx.x * 16 - 8;

    for (int i = t; i < 2 * 34 * TSTR; i += 256) (&D[0][0])[i] = BIGV;
    __syncthreads();

    float cR[4][8];
#pragma unroll
    for (int i = 0; i < 4; ++i) {
        int gr = r0 + rbase + i, gc = c0 + tc;
        bool in = ((unsigned)gr < Hd) && ((unsigned)gc < Wd);
        int p = (gr << 8) + gc;
        float v;
        if (FIRST) {
            int sp = startn[0] * Wd + startn[1];
            v = (in && p != sp) ? BIGV : (in ? 0.0f : BIGV);
        } else {
            v = in ? src[p] : BIGV;
        }
        D[0][(rbase + i + 1) * TSTR + tc + 1] = v;
#pragma unroll
        for (int j = 0; j < 8; ++j)
            cR[i][j] = in ? costP[(j << 16) + p] : BIGV;
    }
    __syncthreads();

#pragma unroll
    for (int it = 0; it < 8; ++it) {
        const float* __restrict__ Dc = D[it & 1];
        float*       __restrict__ Dn = D[1 - (it & 1)];
        const int m = 7 - it;
        if (rbase + 3 >= 8 - m && rbase <= 23 + m) {
            int idx = rbase * TSTR + tc + 1;       // LDS row above first cell
            float a = Dc[idx - 1], b = Dc[idx], cv = Dc[idx + 1];
            idx += TSTR;
            float d = Dc[idx - 1], e = Dc[idx], f = Dc[idx + 1];
#pragma unroll
            for (int i = 0; i < 4; ++i) {
                idx += TSTR;
                float g = Dc[idx - 1], h = Dc[idx], i2 = Dc[idx + 1];
                float best = e;
                best = fminf(best, a  + cR[i][0]);
                best = fminf(best, b  + cR[i][1]);
                best = fminf(best, cv + cR[i][2]);
                best = fminf(best, d  + cR[i][3]);
                best = fminf(best, f  + cR[i][4]);
                best = fminf(best, g  + cR[i][5]);
                best = fminf(best, h  + cR[i][6]);
                best = fminf(best, i2 + cR[i][7]);
                Dn[idx - TSTR] = best;
                a = d; b = e; cv = f;
                d = g; e = h; f = i2;
            }
        }
        __syncthreads();
    }
    // result lands in D[0]; emit 16x16 core
    if (tc >= 8 && tc < 24 && q >= 2 && q < 6) {
#pragma unroll
        for (int i = 0; i < 4; ++i) {
            int lrr = rbase + i;
            int gr = r0 + lrr, gc = c0 + tc;
            float v = D[0][(lrr + 1) * TSTR + tc + 1];
            int p = (gr << 8) + gc;
            if (LAST) outp[p * 10 + 9] = fminf(v, BIGV);
            else      dst[p] = v;
        }
    }
}

// ---------------------------------------------------------------------------
extern "C" void kernel_launch(void* const* d_in, const int* in_sizes, int n_in,
                              void* d_out, int out_size, void* d_ws, size_t ws_size,
                              hipStream_t stream)
{
    const float* feat  = (const float*)d_in[0];
    const float* dlt   = (const float*)d_in[1];
    const float* gmm   = (const float*)d_in[2];
    const float* bta   = (const float*)d_in[3];
    const float* w1    = (const float*)d_in[4];
    const float* b1    = (const float*)d_in[5];
    const float* w2    = (const float*)d_in[6];
    const float* b2    = (const float*)d_in[7];
    const int*   startn= (const int*)d_in[8];
    const int*   endn  = (const int*)d_in[9];
    float* out = (float*)d_out;
    float* ws  = (float*)d_ws;

    float* costP = ws;                    // 8 planes of 65536
    float* geoG  = ws + 8 * 65536;
    float* varG  = geoG + 65536;
    float* omgG  = varG + 65536;
    float* absG  = omgG + 65536;
    float* distA = absG + 65536;
    float* distB = distA + 65536;

    dim3 g16(16, 16);
    k_pixel<<<g16, 256, 0, stream>>>(feat, w1, b1, w2, b2, endn,
                                     out, costP, geoG, varG, omgG, absG);
    k_combine<<<256, 256, 0, stream>>>(geoG, varG, omgG, absG,
                                       dlt, gmm, bta, endn, out);
    // 32 phases x 8 iterations = exactly 256 Jacobi iterations
    k_phase<1, 0><<<g16, 256, 0, stream>>>(nullptr, distA, costP, startn, nullptr);
    float* a = distA; float* bb = distB;
    for (int ph = 1; ph < 31; ++ph) {
        k_phase<0, 0><<<g16, 256, 0, stream>>>(a, bb, costP, startn, nullptr);
        float* tmp = a; a = bb; bb = tmp;
    }
    k_phase<0, 1><<<g16, 256, 0, stream>>>(a, nullptr, costP, startn, out);
}